// Round 1
// baseline (94.160 us; speedup 1.0000x reference)
//
#include <hip/hip_runtime.h>
#include <hip/hip_bf16.h>
#include <stdint.h>

typedef __attribute__((ext_vector_type(4))) float f32x4;
typedef __attribute__((ext_vector_type(4))) unsigned int u32x4;
typedef __attribute__((ext_vector_type(8))) short short8;

#define MFMA16(a, b, c) __builtin_amdgcn_mfma_f32_16x16x32_bf16((a), (b), (c), 0, 0, 0)

__device__ __forceinline__ uint16_t f2bf(float f) {
  __hip_bfloat16 h = __float2bfloat16(f);
  return __builtin_bit_cast(uint16_t, h);
}

// v_rcp_f32-based sigmoid: rcp rel-err ~1ulp << bf16 rounding of every consumer.
__device__ __forceinline__ float fast_sigmoid(float v) {
  return __builtin_amdgcn_rcpf(1.f + __expf(-v));
}

__device__ __forceinline__ short8 cvt8(f32x4 a, f32x4 b) {
  short8 r;
  r[0] = (short)f2bf(a[0]); r[1] = (short)f2bf(a[1]);
  r[2] = (short)f2bf(a[2]); r[3] = (short)f2bf(a[3]);
  r[4] = (short)f2bf(b[0]); r[5] = (short)f2bf(b[1]);
  r[6] = (short)f2bf(b[2]); r[7] = (short)f2bf(b[3]);
  return r;
}

// XOR-swizzled byte offset into row-major [rows][RB bytes] LDS tile (16B slots).
template <int RB>
__device__ __forceinline__ int swzoff(int row, int bcol) {
  constexpr int SLM = (((RB / 16) < 8 ? (RB / 16) : 8)) - 1;
  return row * RB + (bcol ^ ((row & SLM) << 4));
}

// A-fragment (16x32 bf16) from swizzled bf16 LDS tile.
template <int RB>
__device__ __forceinline__ short8 lds_a(const uint16_t* buf, int row0, int k0, int lane) {
  int r = row0 + (lane & 15);
  int bcol = (k0 + ((lane >> 4) << 3)) * 2;
  u32x4 raw = *(const u32x4*)((const char*)buf + swzoff<RB>(r, bcol));
  return __builtin_bit_cast(short8, raw);
}

// Fragment from row-major fp32 M[ld] (coalesced 16-row pattern)
__device__ __forceinline__ short8 load_frag_f32(const float* M, int ld, int r0, int k0, int lane) {
  const float* p = M + (size_t)(r0 + (lane & 15)) * ld + (k0 + ((lane >> 4) << 3));
  f32x4 a = *(const f32x4*)p;
  f32x4 b = *(const f32x4*)(p + 4);
  return cvt8(a, b);
}

// Packed-path B-fragment: one coalesced 16B load from pre-packed d_ws
__device__ __forceinline__ short8 load_b_pk(const char* base, int f, int lane) {
  u32x4 raw = *(const u32x4*)(base + (((size_t)f * 64 + lane) << 4));
  return __builtin_bit_cast(short8, raw);
}

template <bool P>
__device__ __forceinline__ short8 bfrag(const char* wp, const float* W, int K,
                                        int f0, int ntg, int KT, int kt, int lane) {
  if constexpr (P) {
    return load_b_pk(wp, f0 + ntg * KT + kt, lane);
  } else {
    return load_frag_f32(W, K, ntg * 16, kt * 32, lane);
  }
}

// ---- weight pre-pack: 372 fragments x (64 lanes x 16B) = 372 KB in d_ws ----
__global__ void pack_kernel(const float* __restrict__ w1, const float* __restrict__ w2,
                            const float* __restrict__ w3, const float* __restrict__ w4,
                            const float* __restrict__ w5, char* __restrict__ ws) {
  int b = blockIdx.x, lane = threadIdx.x;
  const float* W;
  int K, f0;
  if (b < 256)      { W = w1; K = 512; f0 = 0; }
  else if (b < 320) { W = w2; K = 256; f0 = 256; }
  else if (b < 336) { W = w3; K = 128; f0 = 320; }
  else if (b < 340) { W = w4; K = 64;  f0 = 336; }
  else              { W = w5; K = 32;  f0 = 340; }
  int f = b - f0;
  int KT = K / 32;
  int nt = f / KT, kt = f % KT;
  short8 r = load_frag_f32(W, K, nt * 16, kt * 32, lane);
  *(u32x4*)(ws + (((size_t)b * 64 + lane) << 4)) = __builtin_bit_cast(u32x4, r);
}

// Async-DMA x staging for one K=32 chunk: [64 rows][8 slots of 16B] fp32, ring of 4.
// LDS dest is linear (glds requirement); the slot swizzle (q ^= r&7) is applied to
// the GLOBAL source address (m173 both-sides pattern); reads apply the same XOR.
__device__ __forceinline__ void glds_chunk(const float* xbase, char* sring, int c,
                                           int wid, int lane) {
  char* sb = sring + (size_t)(c & 3) * 8192;
#pragma unroll
  for (int i = 0; i < 2; ++i) {
    int p = wid * 128 + i * 64 + lane;  // 16B slot 0..511
    int r = p >> 3;
    int q = (p & 7) ^ (r & 7);
    const float* src = xbase + (size_t)r * 512 + c * 32 + q * 4;
    __builtin_amdgcn_global_load_lds(
        (const __attribute__((address_space(1))) unsigned int*)src,
        (__attribute__((address_space(3))) unsigned int*)(sb + ((size_t)(wid * 128 + i * 64) << 4)),
        16, 0, 0);
  }
}

// A-fragment (16 rows x 32 k) read from an fp32 swizzled S chunk + cvt to bf16.
__device__ __forceinline__ short8 lds_a_f32(const char* sb, int row0, int lane) {
  int r = row0 + (lane & 15);
  int g = (lane >> 4) << 1;  // logical 16B slot of first 4 floats
  int sw = r & 7;
  const char* rowp = sb + (size_t)r * 128;
  f32x4 a = *(const f32x4*)(rowp + ((g ^ sw) << 4));
  f32x4 b = *(const f32x4*)(rowp + (((g + 1) ^ sw) << 4));
  return cvt8(a, b);
}

#define WAITBAR(VN)                                          \
  asm volatile("s_waitcnt vmcnt(" #VN ")" ::: "memory");     \
  __builtin_amdgcn_s_barrier();

// One L1 K-chunk, software-pipelined B fragments:
//   wait (own glds(C) + B(C) done; deeper glds prefetch stays in flight), barrier,
//   issue B(C+1) BEFORE glds(C+3) (sched_barrier pins the VMEM order so the
//   counted vmcnt at the next barrier never drains a freshly-issued DMA),
//   compute with B(C) already in regs -> no mid-step vmcnt(0) drain.
// Steady-state queue entering barrier C: [g(C+1), B(C), g(C+2)] -> vmcnt(2).
#define KSTEP(C, VN)                                                          \
  {                                                                           \
    WAITBAR(VN);                                                              \
    if ((C) < 15) {                                                           \
      _Pragma("unroll") for (int nt = 0; nt < 4; ++nt)                        \
          bfr[((C) + 1) & 1][nt] =                                            \
              bfrag<P>(wp, w1, 512, 0, wid * 4 + nt, 16, (C) + 1, lane);      \
    }                                                                         \
    __builtin_amdgcn_sched_barrier(0);                                        \
    if ((C) < 13) glds_chunk(xbase, smem, (C) + 3, wid, lane);                \
    char* sc = smem + (size_t)((C) & 3) * 8192;                               \
    _Pragma("unroll") for (int m = 0; m < 4; ++m) {                           \
      short8 a = lds_a_f32(sc, m * 16, lane);                                 \
      _Pragma("unroll") for (int nt = 0; nt < 4; ++nt)                        \
          acc[m][nt] = MFMA16(a, bfr[(C) & 1][nt], acc[m][nt]);               \
    }                                                                         \
  }

// 64 rows/block, 256 threads, 32KB arena -> 4 blocks/CU (16 waves), VGPR cap 128.
template <bool P>
__global__ __launch_bounds__(256, 4) void mlp5_kernel(
    const float* __restrict__ x,
    const float* __restrict__ w1, const float* __restrict__ b1,
    const float* __restrict__ w2, const float* __restrict__ b2,
    const float* __restrict__ w3, const float* __restrict__ b3,
    const float* __restrict__ w4, const float* __restrict__ b4,
    const float* __restrict__ w5, const float* __restrict__ b5,
    const char* __restrict__ wp, float* __restrict__ out) {
  // Arena 32KB (every overlay is protected by an existing barrier):
  //   L1: S ring [0,32K) = 4 x 8KB fp32 chunks (glds DMA)
  //   L1 epilogue (after barrier): H1 [0,32K) overlays S
  //   L2: H1 in; H2 [0,16K) out — overlays H1, write is after the barrier that
  //       follows the last H1 read (was previously at [32K,48K))
  //   L3: H2 in, H3 [16K,24K) out (disjoint from H2; old H1 bytes dead)
  //   L4: H3 in, H4 [24K,28K) out
  //   L5: H4 in
  __shared__ __align__(16) char smem[32 * 1024];
  uint16_t* H1 = (uint16_t*)smem;                // [64][256] bf16, RB=512
  uint16_t* H2 = (uint16_t*)smem;                // [64][128] bf16, RB=256
  uint16_t* H3 = (uint16_t*)(smem + 16 * 1024);  // [64][64]  bf16, RB=128
  uint16_t* H4 = (uint16_t*)(smem + 24 * 1024);  // [64][32]  bf16, RB=64

  const int tid = threadIdx.x;
  const int lane = tid & 63;
  const int wid = tid >> 6;
  const int row0 = blockIdx.x * 64;
  const int lr = (lane >> 4) << 2;
  const int lc = lane & 15;

  // in_size = count_nonzero(x[0])
  int in_size = 0;
#pragma unroll
  for (int j = 0; j < 8; ++j) {
    float v = x[j * 64 + lane];
    in_size += (int)__popcll(__ballot(v != 0.f));
  }

  const float* xbase = x + (size_t)row0 * 512;

  // ---- Layer 1: x[64x512] @ w1[256x512]^T -> h1[64x256]
  // 16 K-chunks of 32, 4-deep DMA ring, B frags pipelined one chunk ahead,
  // one non-draining barrier per chunk.
  f32x4 acc[4][4];
#pragma unroll
  for (int m = 0; m < 4; ++m)
#pragma unroll
    for (int n = 0; n < 4; ++n) acc[m][n] = (f32x4){0.f, 0.f, 0.f, 0.f};

  short8 bfr[2][4];
  glds_chunk(xbase, smem, 0, wid, lane);
#pragma unroll
  for (int nt = 0; nt < 4; ++nt)
    bfr[0][nt] = bfrag<P>(wp, w1, 512, 0, wid * 4 + nt, 16, 0, lane);
  glds_chunk(xbase, smem, 1, wid, lane);
  glds_chunk(xbase, smem, 2, wid, lane);

  KSTEP(0, 4)  KSTEP(1, 2)  KSTEP(2, 2)  KSTEP(3, 2)
  KSTEP(4, 2)  KSTEP(5, 2)  KSTEP(6, 2)  KSTEP(7, 2)
  KSTEP(8, 2)  KSTEP(9, 2)  KSTEP(10, 2) KSTEP(11, 2)
  KSTEP(12, 2) KSTEP(13, 2) KSTEP(14, 0) KSTEP(15, 0)

  // Hoist L2's weight fragments (L2$ latency hides under barrier + epilogue VALU)
  short8 bfr2[2][8];
#pragma unroll
  for (int n = 0; n < 2; ++n)
#pragma unroll
    for (int kt = 0; kt < 8; ++kt)
      bfr2[n][kt] = bfrag<P>(wp, w2, 256, 256, wid * 2 + n, 8, kt, lane);

  __syncthreads();  // all S-ring reads done before H1 overlays [0,32K)

  // L1 epilogue: bias + sigmoid -> H1
#pragma unroll
  for (int n = 0; n < 4; ++n) {
    const int ncol = wid * 64 + n * 16;
    const float bv = b1[ncol + lc];
#pragma unroll
    for (int m = 0; m < 4; ++m)
#pragma unroll
      for (int i = 0; i < 4; ++i) {
        float v = fast_sigmoid(acc[m][n][i] + bv);
        *(uint16_t*)((char*)H1 + swzoff<512>(m * 16 + lr + i, (ncol + lc) * 2)) = f2bf(v);
      }
  }
  __syncthreads();

  // ---- Layer 2: h1[64x256] -> h2[64x128]; wave cols wid*32 (2 nt), 4 mt, KT=8
  {
    f32x4 acc2[4][2];
#pragma unroll
    for (int m = 0; m < 4; ++m)
#pragma unroll
      for (int n = 0; n < 2; ++n) acc2[m][n] = (f32x4){0.f, 0.f, 0.f, 0.f};
#pragma unroll
    for (int m = 0; m < 4; ++m) {
#pragma unroll
      for (int kt = 0; kt < 8; ++kt) {
        short8 afr = lds_a<512>(H1, m * 16, kt * 32, lane);
        acc2[m][0] = MFMA16(afr, bfr2[0][kt], acc2[m][0]);
        acc2[m][1] = MFMA16(afr, bfr2[1][kt], acc2[m][1]);
      }
    }
    // Hoist L3 weights
    short8 bfr3[4];
#pragma unroll
    for (int kt = 0; kt < 4; ++kt)
      bfr3[kt] = bfrag<P>(wp, w3, 128, 320, wid, 4, kt, lane);
    __syncthreads();  // REQUIRED: last H1 read done before H2 overlays [0,16K)
#pragma unroll
    for (int n = 0; n < 2; ++n) {
      const int ncol = wid * 32 + n * 16;
      const float bv = b2[ncol + lc];
#pragma unroll
      for (int m = 0; m < 4; ++m)
#pragma unroll
        for (int i = 0; i < 4; ++i) {
          float v = fast_sigmoid(acc2[m][n][i] + bv);
          *(uint16_t*)((char*)H2 + swzoff<256>(m * 16 + lr + i, (ncol + lc) * 2)) = f2bf(v);
        }
    }
    __syncthreads();

    // ---- Layer 3: h2[64x128] -> h3[64x64]; wave col-tile wid (1 nt), 4 mt, KT=4
    f32x4 acc3[4];
#pragma unroll
    for (int m = 0; m < 4; ++m) acc3[m] = (f32x4){0.f, 0.f, 0.f, 0.f};
#pragma unroll
    for (int m = 0; m < 4; ++m)
#pragma unroll
      for (int kt = 0; kt < 4; ++kt) {
        short8 afr = lds_a<256>(H2, m * 16, kt * 32, lane);
        acc3[m] = MFMA16(afr, bfr3[kt], acc3[m]);
      }
    // Hoist L4 weights
    short8 bfr4[2];
#pragma unroll
    for (int kt = 0; kt < 2; ++kt)
      bfr4[kt] = bfrag<P>(wp, w4, 64, 336, wid & 1, 2, kt, lane);
    {
      const int ncol = wid * 16;
      const float bv = b3[ncol + lc];
#pragma unroll
      for (int m = 0; m < 4; ++m)
#pragma unroll
        for (int i = 0; i < 4; ++i) {
          float v = fast_sigmoid(acc3[m][i] + bv);
          *(uint16_t*)((char*)H3 + swzoff<128>(m * 16 + lr + i, (ncol + lc) * 2)) = f2bf(v);
        }
    }
    __syncthreads();

    // ---- Layer 4: h3[64x64] -> h4[64x32]; waves 2x2: rows wm*32 (2 mt), col wn*16, KT=2
    const int wm = wid >> 1, wn = wid & 1;
    f32x4 acc4[2];
#pragma unroll
    for (int mt = 0; mt < 2; ++mt) acc4[mt] = (f32x4){0.f, 0.f, 0.f, 0.f};
#pragma unroll
    for (int mt = 0; mt < 2; ++mt)
#pragma unroll
      for (int kt = 0; kt < 2; ++kt) {
        short8 afr = lds_a<128>(H3, wm * 32 + mt * 16, kt * 32, lane);
        acc4[mt] = MFMA16(afr, bfr4[kt], acc4[mt]);
      }
    // Hoist L5 weights
    short8 bfr5[8];
#pragma unroll
    for (int nt = 0; nt < 8; ++nt)
      bfr5[nt] = bfrag<P>(wp, w5, 32, 340, wid * 8 + nt, 1, 0, lane);
    {
      const int ncol = wn * 16;
      const float bv = b4[ncol + lc];
#pragma unroll
      for (int mt = 0; mt < 2; ++mt)
#pragma unroll
        for (int i = 0; i < 4; ++i) {
          float v = fast_sigmoid(acc4[mt][i] + bv);
          *(uint16_t*)((char*)H4 + swzoff<64>(wm * 32 + mt * 16 + lr + i, (ncol + lc) * 2)) = f2bf(v);
        }
    }
    __syncthreads();

    // ---- Layer 5: h4[64x32] -> out[64x512]; wave cols wid*128 (8 nt), 4 mt, KT=1
#pragma unroll
    for (int m = 0; m < 4; ++m) {
      short8 afr = lds_a<64>(H4, m * 16, 0, lane);
#pragma unroll
      for (int nt = 0; nt < 8; ++nt) {
        f32x4 av = MFMA16(afr, bfr5[nt], ((f32x4){0.f, 0.f, 0.f, 0.f}));
        const int col = wid * 128 + nt * 16 + lc;
        const float bv = b5[col];
        const bool keep = col < in_size;
#pragma unroll
        for (int i = 0; i < 4; ++i) {
          float v = keep ? (av[i] + bv) : 0.f;
          out[(size_t)(row0 + m * 16 + lr + i) * 512 + col] = v;
        }
      }
    }
  }
}

extern "C" void kernel_launch(void* const* d_in, const int* in_sizes, int n_in,
                              void* d_out, int out_size, void* d_ws, size_t ws_size,
                              hipStream_t stream) {
  const float* x  = (const float*)d_in[0];
  const float* w1 = (const float*)d_in[1];
  const float* b1 = (const float*)d_in[2];
  const float* w2 = (const float*)d_in[3];
  const float* b2 = (const float*)d_in[4];
  const float* w3 = (const float*)d_in[5];
  const float* b3 = (const float*)d_in[6];
  const float* w4 = (const float*)d_in[7];
  const float* b4 = (const float*)d_in[8];
  const float* w5 = (const float*)d_in[9];
  const float* b5 = (const float*)d_in[10];
  float* out = (float*)d_out;

  dim3 grid(65536 / 64);
  dim3 block(256);
  const bool packed = ws_size >= (size_t)(372 * 1024);
  if (packed) {
    pack_kernel<<<372, 64, 0, stream>>>(w1, w2, w3, w4, w5, (char*)d_ws);
    mlp5_kernel<true><<<grid, block, 0, stream>>>(x, w1, b1, w2, b2, w3, b3, w4, b4,
                                                  w5, b5, (const char*)d_ws, out);
  } else {
    mlp5_kernel<false><<<grid, block, 0, stream>>>(x, w1, b1, w2, b2, w3, b3, w4, b4,
                                                   w5, b5, nullptr, out);
  }
}

// Round 2
// 76.907 us; speedup vs baseline: 1.2243x; 1.2243x over previous
//
#include <hip/hip_runtime.h>
#include <hip/hip_bf16.h>
#include <stdint.h>

typedef __attribute__((ext_vector_type(4))) float f32x4;
typedef __attribute__((ext_vector_type(4))) unsigned int u32x4;
typedef __attribute__((ext_vector_type(8))) short short8;

#define MFMA16(a, b, c) __builtin_amdgcn_mfma_f32_16x16x32_bf16((a), (b), (c), 0, 0, 0)

__device__ __forceinline__ uint16_t f2bf(float f) {
  __hip_bfloat16 h = __float2bfloat16(f);
  return __builtin_bit_cast(uint16_t, h);
}

// v_rcp_f32-based sigmoid: rcp rel-err ~1ulp << bf16 rounding of every consumer.
__device__ __forceinline__ float fast_sigmoid(float v) {
  return __builtin_amdgcn_rcpf(1.f + __expf(-v));
}

__device__ __forceinline__ short8 cvt8(f32x4 a, f32x4 b) {
  short8 r;
  r[0] = (short)f2bf(a[0]); r[1] = (short)f2bf(a[1]);
  r[2] = (short)f2bf(a[2]); r[3] = (short)f2bf(a[3]);
  r[4] = (short)f2bf(b[0]); r[5] = (short)f2bf(b[1]);
  r[6] = (short)f2bf(b[2]); r[7] = (short)f2bf(b[3]);
  return r;
}

// XOR-swizzled byte offset into row-major [rows][RB bytes] LDS tile (16B slots).
template <int RB>
__device__ __forceinline__ int swzoff(int row, int bcol) {
  constexpr int SLM = (((RB / 16) < 8 ? (RB / 16) : 8)) - 1;
  return row * RB + (bcol ^ ((row & SLM) << 4));
}

// A-fragment (16x32 bf16) from swizzled bf16 LDS tile.
template <int RB>
__device__ __forceinline__ short8 lds_a(const uint16_t* buf, int row0, int k0, int lane) {
  int r = row0 + (lane & 15);
  int bcol = (k0 + ((lane >> 4) << 3)) * 2;
  u32x4 raw = *(const u32x4*)((const char*)buf + swzoff<RB>(r, bcol));
  return __builtin_bit_cast(short8, raw);
}

// Fragment from row-major fp32 M[ld] (coalesced 16-row pattern)
__device__ __forceinline__ short8 load_frag_f32(const float* M, int ld, int r0, int k0, int lane) {
  const float* p = M + (size_t)(r0 + (lane & 15)) * ld + (k0 + ((lane >> 4) << 3));
  f32x4 a = *(const f32x4*)p;
  f32x4 b = *(const f32x4*)(p + 4);
  return cvt8(a, b);
}

// Packed-path B-fragment: one coalesced 16B load from pre-packed d_ws
__device__ __forceinline__ short8 load_b_pk(const char* base, int f, int lane) {
  u32x4 raw = *(const u32x4*)(base + (((size_t)f * 64 + lane) << 4));
  return __builtin_bit_cast(short8, raw);
}

template <bool P>
__device__ __forceinline__ short8 bfrag(const char* wp, const float* W, int K,
                                        int f0, int ntg, int KT, int kt, int lane) {
  if constexpr (P) {
    return load_b_pk(wp, f0 + ntg * KT + kt, lane);
  } else {
    return load_frag_f32(W, K, ntg * 16, kt * 32, lane);
  }
}

// ---- weight pre-pack: 372 fragments x (64 lanes x 16B) = 372 KB in d_ws ----
__global__ void pack_kernel(const float* __restrict__ w1, const float* __restrict__ w2,
                            const float* __restrict__ w3, const float* __restrict__ w4,
                            const float* __restrict__ w5, char* __restrict__ ws) {
  int b = blockIdx.x, lane = threadIdx.x;
  const float* W;
  int K, f0;
  if (b < 256)      { W = w1; K = 512; f0 = 0; }
  else if (b < 320) { W = w2; K = 256; f0 = 256; }
  else if (b < 336) { W = w3; K = 128; f0 = 320; }
  else if (b < 340) { W = w4; K = 64;  f0 = 336; }
  else              { W = w5; K = 32;  f0 = 340; }
  int f = b - f0;
  int KT = K / 32;
  int nt = f / KT, kt = f % KT;
  short8 r = load_frag_f32(W, K, nt * 16, kt * 32, lane);
  *(u32x4*)(ws + (((size_t)b * 64 + lane) << 4)) = __builtin_bit_cast(u32x4, r);
}

// Async-DMA x staging for one K=32 chunk: [64 rows][8 slots of 16B] fp32, ring of 4.
// LDS dest is linear (glds requirement); the slot swizzle (q ^= r&7) is applied to
// the GLOBAL source address (m173 both-sides pattern); reads apply the same XOR.
__device__ __forceinline__ void glds_chunk(const float* xbase, char* sring, int c,
                                           int wid, int lane) {
  char* sb = sring + (size_t)(c & 3) * 8192;
#pragma unroll
  for (int i = 0; i < 2; ++i) {
    int p = wid * 128 + i * 64 + lane;  // 16B slot 0..511
    int r = p >> 3;
    int q = (p & 7) ^ (r & 7);
    const float* src = xbase + (size_t)r * 512 + c * 32 + q * 4;
    __builtin_amdgcn_global_load_lds(
        (const __attribute__((address_space(1))) unsigned int*)src,
        (__attribute__((address_space(3))) unsigned int*)(sb + ((size_t)(wid * 128 + i * 64) << 4)),
        16, 0, 0);
  }
}

// A-fragment (16 rows x 32 k) read from an fp32 swizzled S chunk + cvt to bf16.
__device__ __forceinline__ short8 lds_a_f32(const char* sb, int row0, int lane) {
  int r = row0 + (lane & 15);
  int g = (lane >> 4) << 1;  // logical 16B slot of first 4 floats
  int sw = r & 7;
  const char* rowp = sb + (size_t)r * 128;
  f32x4 a = *(const f32x4*)(rowp + ((g ^ sw) << 4));
  f32x4 b = *(const f32x4*)(rowp + (((g + 1) ^ sw) << 4));
  return cvt8(a, b);
}

#define WAITBAR(VN)                                          \
  asm volatile("s_waitcnt vmcnt(" #VN ")" ::: "memory");     \
  __builtin_amdgcn_s_barrier();

// One L1 K-chunk, software-pipelined B fragments:
//   wait (own glds(C) + B(C) done; deeper glds prefetch stays in flight), barrier,
//   issue B(C+1) BEFORE glds(C+3) (sched_barrier pins the VMEM order so the
//   counted vmcnt at the next barrier never drains a freshly-issued DMA),
//   compute with B(C) already in regs -> no mid-step vmcnt(0) drain.
// Steady-state queue entering barrier C: [g(C+1), B(C), g(C+2)] -> vmcnt(2).
#define KSTEP(C, VN)                                                          \
  {                                                                           \
    WAITBAR(VN);                                                              \
    if ((C) < 15) {                                                           \
      _Pragma("unroll") for (int nt = 0; nt < 4; ++nt)                        \
          bfr[((C) + 1) & 1][nt] =                                            \
              bfrag<P>(wp, w1, 512, 0, wid * 4 + nt, 16, (C) + 1, lane);      \
    }                                                                         \
    __builtin_amdgcn_sched_barrier(0);                                        \
    if ((C) < 13) glds_chunk(xbase, smem, (C) + 3, wid, lane);                \
    char* sc = smem + (size_t)((C) & 3) * 8192;                               \
    _Pragma("unroll") for (int m = 0; m < 4; ++m) {                           \
      short8 a = lds_a_f32(sc, m * 16, lane);                                 \
      _Pragma("unroll") for (int nt = 0; nt < 4; ++nt)                        \
          acc[m][nt] = MFMA16(a, bfr[(C) & 1][nt], acc[m][nt]);               \
    }                                                                         \
  }

// 64 rows/block, 256 threads, 32KB arena.
// __launch_bounds__(256,3): VGPR cap 168 — round 1 showed that (256,4)'s cap of
// 128 forces spills (VGPR_Count=64 + ~100MB scratch HBM traffic). With ~110 VGPR
// actual and 32KB LDS, occupancy is 4-5 blocks/CU with zero scratch.
template <bool P>
__global__ __launch_bounds__(256, 3) void mlp5_kernel(
    const float* __restrict__ x,
    const float* __restrict__ w1, const float* __restrict__ b1,
    const float* __restrict__ w2, const float* __restrict__ b2,
    const float* __restrict__ w3, const float* __restrict__ b3,
    const float* __restrict__ w4, const float* __restrict__ b4,
    const float* __restrict__ w5, const float* __restrict__ b5,
    const char* __restrict__ wp, float* __restrict__ out) {
  // Arena 32KB (every overlay is protected by an existing barrier):
  //   L1: S ring [0,32K) = 4 x 8KB fp32 chunks (glds DMA)
  //   L1 epilogue (after barrier): H1 [0,32K) overlays S
  //   L2: H1 in; H2 [0,16K) out — overlays H1, write is after the barrier that
  //       follows the last H1 read
  //   L3: H2 in, H3 [16K,24K) out (disjoint from H2; old H1 bytes dead)
  //   L4: H3 in, H4 [24K,28K) out
  //   L5: H4 in
  __shared__ __align__(16) char smem[32 * 1024];
  uint16_t* H1 = (uint16_t*)smem;                // [64][256] bf16, RB=512
  uint16_t* H2 = (uint16_t*)smem;                // [64][128] bf16, RB=256
  uint16_t* H3 = (uint16_t*)(smem + 16 * 1024);  // [64][64]  bf16, RB=128
  uint16_t* H4 = (uint16_t*)(smem + 24 * 1024);  // [64][32]  bf16, RB=64

  const int tid = threadIdx.x;
  const int lane = tid & 63;
  const int wid = tid >> 6;
  const int row0 = blockIdx.x * 64;
  const int lr = (lane >> 4) << 2;
  const int lc = lane & 15;

  // in_size = count_nonzero(x[0])
  int in_size = 0;
#pragma unroll
  for (int j = 0; j < 8; ++j) {
    float v = x[j * 64 + lane];
    in_size += (int)__popcll(__ballot(v != 0.f));
  }

  const float* xbase = x + (size_t)row0 * 512;

  // ---- Layer 1: x[64x512] @ w1[256x512]^T -> h1[64x256]
  // 16 K-chunks of 32, 4-deep DMA ring, B frags pipelined one chunk ahead,
  // one non-draining barrier per chunk.
  f32x4 acc[4][4];
#pragma unroll
  for (int m = 0; m < 4; ++m)
#pragma unroll
    for (int n = 0; n < 4; ++n) acc[m][n] = (f32x4){0.f, 0.f, 0.f, 0.f};

  short8 bfr[2][4];
  glds_chunk(xbase, smem, 0, wid, lane);
#pragma unroll
  for (int nt = 0; nt < 4; ++nt)
    bfr[0][nt] = bfrag<P>(wp, w1, 512, 0, wid * 4 + nt, 16, 0, lane);
  glds_chunk(xbase, smem, 1, wid, lane);
  glds_chunk(xbase, smem, 2, wid, lane);

  KSTEP(0, 4)  KSTEP(1, 2)  KSTEP(2, 2)  KSTEP(3, 2)
  KSTEP(4, 2)  KSTEP(5, 2)  KSTEP(6, 2)  KSTEP(7, 2)
  KSTEP(8, 2)  KSTEP(9, 2)  KSTEP(10, 2) KSTEP(11, 2)
  KSTEP(12, 2) KSTEP(13, 2) KSTEP(14, 0) KSTEP(15, 0)

  // Hoist L2's weight fragments (L2$ latency hides under barrier + epilogue VALU)
  short8 bfr2[2][8];
#pragma unroll
  for (int n = 0; n < 2; ++n)
#pragma unroll
    for (int kt = 0; kt < 8; ++kt)
      bfr2[n][kt] = bfrag<P>(wp, w2, 256, 256, wid * 2 + n, 8, kt, lane);

  __syncthreads();  // all S-ring reads done before H1 overlays [0,32K)

  // L1 epilogue: bias + sigmoid -> H1
#pragma unroll
  for (int n = 0; n < 4; ++n) {
    const int ncol = wid * 64 + n * 16;
    const float bv = b1[ncol + lc];
#pragma unroll
    for (int m = 0; m < 4; ++m)
#pragma unroll
      for (int i = 0; i < 4; ++i) {
        float v = fast_sigmoid(acc[m][n][i] + bv);
        *(uint16_t*)((char*)H1 + swzoff<512>(m * 16 + lr + i, (ncol + lc) * 2)) = f2bf(v);
      }
  }
  __syncthreads();

  // ---- Layer 2: h1[64x256] -> h2[64x128]; wave cols wid*32 (2 nt), 4 mt, KT=8
  {
    f32x4 acc2[4][2];
#pragma unroll
    for (int m = 0; m < 4; ++m)
#pragma unroll
      for (int n = 0; n < 2; ++n) acc2[m][n] = (f32x4){0.f, 0.f, 0.f, 0.f};
#pragma unroll
    for (int m = 0; m < 4; ++m) {
#pragma unroll
      for (int kt = 0; kt < 8; ++kt) {
        short8 afr = lds_a<512>(H1, m * 16, kt * 32, lane);
        acc2[m][0] = MFMA16(afr, bfr2[0][kt], acc2[m][0]);
        acc2[m][1] = MFMA16(afr, bfr2[1][kt], acc2[m][1]);
      }
    }
    // Hoist L3 weights
    short8 bfr3[4];
#pragma unroll
    for (int kt = 0; kt < 4; ++kt)
      bfr3[kt] = bfrag<P>(wp, w3, 128, 320, wid, 4, kt, lane);
    __syncthreads();  // REQUIRED: last H1 read done before H2 overlays [0,16K)
#pragma unroll
    for (int n = 0; n < 2; ++n) {
      const int ncol = wid * 32 + n * 16;
      const float bv = b2[ncol + lc];
#pragma unroll
      for (int m = 0; m < 4; ++m)
#pragma unroll
        for (int i = 0; i < 4; ++i) {
          float v = fast_sigmoid(acc2[m][n][i] + bv);
          *(uint16_t*)((char*)H2 + swzoff<256>(m * 16 + lr + i, (ncol + lc) * 2)) = f2bf(v);
        }
    }
    __syncthreads();

    // ---- Layer 3: h2[64x128] -> h3[64x64]; wave col-tile wid (1 nt), 4 mt, KT=4
    f32x4 acc3[4];
#pragma unroll
    for (int m = 0; m < 4; ++m) acc3[m] = (f32x4){0.f, 0.f, 0.f, 0.f};
#pragma unroll
    for (int m = 0; m < 4; ++m)
#pragma unroll
      for (int kt = 0; kt < 4; ++kt) {
        short8 afr = lds_a<256>(H2, m * 16, kt * 32, lane);
        acc3[m] = MFMA16(afr, bfr3[kt], acc3[m]);
      }
    // Hoist L4 weights
    short8 bfr4[2];
#pragma unroll
    for (int kt = 0; kt < 2; ++kt)
      bfr4[kt] = bfrag<P>(wp, w4, 64, 336, wid & 1, 2, kt, lane);
    {
      const int ncol = wid * 16;
      const float bv = b3[ncol + lc];
#pragma unroll
      for (int m = 0; m < 4; ++m)
#pragma unroll
        for (int i = 0; i < 4; ++i) {
          float v = fast_sigmoid(acc3[m][i] + bv);
          *(uint16_t*)((char*)H3 + swzoff<128>(m * 16 + lr + i, (ncol + lc) * 2)) = f2bf(v);
        }
    }
    __syncthreads();

    // ---- Layer 4: h3[64x64] -> h4[64x32]; waves 2x2: rows wm*32 (2 mt), col wn*16, KT=2
    const int wm = wid >> 1, wn = wid & 1;
    f32x4 acc4[2];
#pragma unroll
    for (int mt = 0; mt < 2; ++mt) acc4[mt] = (f32x4){0.f, 0.f, 0.f, 0.f};
#pragma unroll
    for (int mt = 0; mt < 2; ++mt)
#pragma unroll
      for (int kt = 0; kt < 2; ++kt) {
        short8 afr = lds_a<128>(H3, wm * 32 + mt * 16, kt * 32, lane);
        acc4[mt] = MFMA16(afr, bfr4[kt], acc4[mt]);
      }
    // Hoist L5 weights
    short8 bfr5[8];
#pragma unroll
    for (int nt = 0; nt < 8; ++nt)
      bfr5[nt] = bfrag<P>(wp, w5, 32, 340, wid * 8 + nt, 1, 0, lane);
    {
      const int ncol = wn * 16;
      const float bv = b4[ncol + lc];
#pragma unroll
      for (int mt = 0; mt < 2; ++mt)
#pragma unroll
        for (int i = 0; i < 4; ++i) {
          float v = fast_sigmoid(acc4[mt][i] + bv);
          *(uint16_t*)((char*)H4 + swzoff<64>(wm * 32 + mt * 16 + lr + i, (ncol + lc) * 2)) = f2bf(v);
        }
    }
    __syncthreads();

    // ---- Layer 5: h4[64x32] -> out[64x512]; wave cols wid*128 (8 nt), 4 mt, KT=1
#pragma unroll
    for (int m = 0; m < 4; ++m) {
      short8 afr = lds_a<64>(H4, m * 16, 0, lane);
#pragma unroll
      for (int nt = 0; nt < 8; ++nt) {
        f32x4 av = MFMA16(afr, bfr5[nt], ((f32x4){0.f, 0.f, 0.f, 0.f}));
        const int col = wid * 128 + nt * 16 + lc;
        const float bv = b5[col];
        const bool keep = col < in_size;
#pragma unroll
        for (int i = 0; i < 4; ++i) {
          float v = keep ? (av[i] + bv) : 0.f;
          out[(size_t)(row0 + m * 16 + lr + i) * 512 + col] = v;
        }
      }
    }
  }
}

extern "C" void kernel_launch(void* const* d_in, const int* in_sizes, int n_in,
                              void* d_out, int out_size, void* d_ws, size_t ws_size,
                              hipStream_t stream) {
  const float* x  = (const float*)d_in[0];
  const float* w1 = (const float*)d_in[1];
  const float* b1 = (const float*)d_in[2];
  const float* w2 = (const float*)d_in[3];
  const float* b2 = (const float*)d_in[4];
  const float* w3 = (const float*)d_in[5];
  const float* b3 = (const float*)d_in[6];
  const float* w4 = (const float*)d_in[7];
  const float* b4 = (const float*)d_in[8];
  const float* w5 = (const float*)d_in[9];
  const float* b5 = (const float*)d_in[10];
  float* out = (float*)d_out;

  dim3 grid(65536 / 64);
  dim3 block(256);
  const bool packed = ws_size >= (size_t)(372 * 1024);
  if (packed) {
    pack_kernel<<<372, 64, 0, stream>>>(w1, w2, w3, w4, w5, (char*)d_ws);
    mlp5_kernel<true><<<grid, block, 0, stream>>>(x, w1, b1, w2, b2, w3, b3, w4, b4,
                                                  w5, b5, (const char*)d_ws, out);
  } else {
    mlp5_kernel<false><<<grid, block, 0, stream>>>(x, w1, b1, w2, b2, w3, b3, w4, b4,
                                                   w5, b5, nullptr, out);
  }
}